// Round 11
// baseline (106.510 us; speedup 1.0000x reference)
//
#include <hip/hip_runtime.h>

// Problem constants
#define NB     64      // batch
#define TT     2048    // time
#define INQ    8       // input size
#define CC     2       // channels
#define MM     10      // hidden m
#define ROWP   12      // padded row floats (48 B)
#define MATS   124     // matrix stride in LDS tree (124%32=28)
#define SKST   12      // skq row stride floats (48 B, b128-aligned)
#define BLK    512     // threads per block (8 waves)
#define SEGS   96      // 8 waves * 12 five-lane groups
#define SLEN   6       // steps per segment (padded timeline 2304 = 4*96*6)
#define NCHK   4       // chunks per chain -> grid 512 = 2 blocks/CU
#define NCHAIN (NB*CC)
#define SLOT   120     // scratch slot floats per group (2 parities x 60)

typedef float v2f __attribute__((ext_vector_type(2)));

static_assert(SEGS * MATS >= 97 * SLOT, "scratch overlay must fit tree buffer");

// Upper-triangle index for (k,j), k<j, into 45-element array
__device__ __forceinline__ constexpr int triIdx(int k, int j) {
    return k * 10 + j - ((k + 1) * (k + 2)) / 2;
}

// One Taylor row-stream, packed pair of rows: t = S*G; A = t; R += cj*t.
// Row r of S*G depends only on row r of S -> in-place safe (S may alias A).
__device__ __forceinline__ void trow_pk(const float* __restrict__ Tri,
                                        v2f* A, v2f* R, const v2f* S, float cj) {
    v2f t[MM];
    t[0] = -S[1] * Tri[triIdx(0, 1)];
    #pragma unroll
    for (int j = 1; j < MM; ++j) t[j] = S[0] * Tri[triIdx(0, j)];
    #pragma unroll
    for (int k = 1; k < MM; ++k) {
        const v2f a = S[k];
        #pragma unroll
        for (int j = 0; j < MM; ++j) {
            if (k == j) continue;
            if (j == 0 && k == 1) continue;
            if (j > k) t[j] += a * Tri[triIdx(k, j)];
            else       t[j] -= a * Tri[triIdx(j, k)];
        }
    }
    #pragma unroll
    for (int j = 0; j < MM; ++j) { A[j] = t[j]; R[j] += cj * t[j]; }
}

// KTAY=5 Taylor burst on the packed row-pair accumulator.
__device__ __forceinline__ void taylor5(const float* __restrict__ Tri, v2f* R01) {
    __builtin_amdgcn_s_setprio(1);
    v2f A01[MM];
    trow_pk(Tri, A01, R01, R01, 1.0f);
    trow_pk(Tri, A01, R01, A01, 0.5f);
    trow_pk(Tri, A01, R01, A01, 0.16666667f);
    trow_pk(Tri, A01, R01, A01, 0.041666668f);
    trow_pk(Tri, A01, R01, A01, 0.0083333338f);
    __builtin_amdgcn_s_setprio(0);
}

// tvv for one step: clamped x loads, dx, 9 dot-products against skq rows.
__device__ __forceinline__ void compute_tvv(const float4* __restrict__ px, int t,
                                            const float* __restrict__ srow,
                                            float* __restrict__ tvv) {
    const int tc = (t     > TT - 1) ? TT - 1 : t;
    const int t1 = (t + 1 > TT - 1) ? TT - 1 : t + 1;
    const float4 a0 = px[2 * tc], a1 = px[2 * tc + 1];
    const float4 b0 = px[2 * t1], b1 = px[2 * t1 + 1];
    float dx[INQ];
    dx[0] = b0.x - a0.x; dx[1] = b0.y - a0.y;
    dx[2] = b0.z - a0.z; dx[3] = b0.w - a0.w;
    dx[4] = b1.x - a1.x; dx[5] = b1.y - a1.y;
    dx[6] = b1.z - a1.z; dx[7] = b1.w - a1.w;
    #pragma unroll
    for (int i = 0; i < 9; ++i) {
        const float4 s0 = *reinterpret_cast<const float4*>(srow + i * SKST);
        const float4 s1 = *reinterpret_cast<const float4*>(srow + i * SKST + 4);
        tvv[i] = dx[0] * s0.x + dx[1] * s0.y + dx[2] * s0.z + dx[3] * s0.w
               + dx[4] * s1.x + dx[5] * s1.y + dx[6] * s1.z + dx[7] * s1.w;
    }
}

// Stage 9 tvv to the group scratch slot: 2 b128 + 1 b32 (48B-aligned lane slot).
__device__ __forceinline__ void store_tvv(float* __restrict__ dst, int r,
                                          const float* __restrict__ tvv) {
    *reinterpret_cast<float4*>(dst + 12 * r)     = make_float4(tvv[0], tvv[1], tvv[2], tvv[3]);
    *reinterpret_cast<float4*>(dst + 12 * r + 4) = make_float4(tvv[4], tvv[5], tvv[6], tvv[7]);
    dst[12 * r + 8] = tvv[8];
}

// Gather the group's 45 entries: 5 x (b128, b128, b32).
__device__ __forceinline__ void load_tri(const float* __restrict__ src,
                                         float* __restrict__ Tri) {
    #pragma unroll
    for (int q2 = 0; q2 < 5; ++q2) {
        const float4 u0 = *reinterpret_cast<const float4*>(src + 12 * q2);
        const float4 u1 = *reinterpret_cast<const float4*>(src + 12 * q2 + 4);
        const float  u2 = src[12 * q2 + 8];
        Tri[9 * q2 + 0] = u0.x; Tri[9 * q2 + 1] = u0.y;
        Tri[9 * q2 + 2] = u0.z; Tri[9 * q2 + 3] = u0.w;
        Tri[9 * q2 + 4] = u1.x; Tri[9 * q2 + 5] = u1.y;
        Tri[9 * q2 + 6] = u1.z; Tri[9 * q2 + 7] = u1.w;
        Tri[9 * q2 + 8] = u2;
    }
}

// 2-lane pair combine: buf[ls] <- buf[ls] * buf[rs] (pq = which 5-row half)
__device__ __forceinline__ void pair_combine(float* buf_s, int ls, int rs, int pq) {
    float lrow[5][MM];
    #pragma unroll
    for (int r = 0; r < 5; ++r) {
        const float4* lr = reinterpret_cast<const float4*>(
            &buf_s[ls * MATS + (pq * 5 + r) * ROWP]);
        const float4 a = lr[0], b = lr[1], c4 = lr[2];
        lrow[r][0] = a.x;  lrow[r][1] = a.y;  lrow[r][2] = a.z;  lrow[r][3] = a.w;
        lrow[r][4] = b.x;  lrow[r][5] = b.y;  lrow[r][6] = b.z;  lrow[r][7] = b.w;
        lrow[r][8] = c4.x; lrow[r][9] = c4.y;
    }
    float d[5][MM];
    #pragma unroll
    for (int r = 0; r < 5; ++r)
        #pragma unroll
        for (int j = 0; j < MM; ++j)
            d[r][j] = 0.0f;
    #pragma unroll
    for (int k = 0; k < MM; ++k) {
        const float4* rr = reinterpret_cast<const float4*>(&buf_s[rs * MATS + k * ROWP]);
        const float4 a = rr[0], b = rr[1], c4 = rr[2];
        float rrow[MM];
        rrow[0] = a.x;  rrow[1] = a.y;  rrow[2] = a.z;  rrow[3] = a.w;
        rrow[4] = b.x;  rrow[5] = b.y;  rrow[6] = b.z;  rrow[7] = b.w;
        rrow[8] = c4.x; rrow[9] = c4.y;
        #pragma unroll
        for (int r = 0; r < 5; ++r) {
            const float lv = lrow[r][k];
            #pragma unroll
            for (int j = 0; j < MM; ++j)
                d[r][j] += lv * rrow[j];
        }
    }
    float* dst = &buf_s[ls * MATS + pq * 5 * ROWP];
    #pragma unroll
    for (int r = 0; r < 5; ++r) {
        float4* drow = reinterpret_cast<float4*>(dst + r * ROWP);
        drow[0] = make_float4(d[r][0], d[r][1], d[r][2], d[r][3]);
        drow[1] = make_float4(d[r][4], d[r][5], d[r][6], d[r][7]);
        drow[2] = make_float4(d[r][8], d[r][9], 0.0f, 0.0f);
    }
}

// r22 (resubmit — prior run died to container-level infra failure, no
// kernel verdict; audited again: LDS 50.2KB x2 = 100KB <= 160KB, VGPR
// 104 <= 128 cap, clamped indices, uniform barriers — no hazard).
// Occupancy retest POST-diet. Pipe budget/step/CU at r21: VALU ~3100
// cyc, LDS ~3400 cyc, wall ~7700 -> ~45% dependency slack with only
// 2 waves/SIMD. r17's occupancy null was PRE-diet (504 LDS ops/step/CU
// saturated the crossbar; extra waves had no pipe to run on). Post-diet
// (288 ops) there is headroom -> 2 blocks/CU: NCHK=4, SLEN=6, grid 512.
// Cost: 12.5% timeline pad (2304) vs filling ~45% idle; blocks drift so
// one block's Taylor overlaps the other's tree. VGPR 104 <= 128 cap at
// (512,2) (r16-verified semantics: min-BLOCKS/CU) -> no spill expected
// (litmus: FETCH ~4.5-6 MB, WRITE < 1 MB). Diet + parity-pipeline body
// unchanged from r21; KTAY=5 unchanged. K2 = dev_tree4 (r12's, known).
// Decision rule: serial >= 38 us kills occupancy for good -> next is
// BLK=256 + srow-in-regs (+KTAY=4).
__global__ __launch_bounds__(BLK, 2)
void dev_serial(const float* __restrict__ x,
                const float* __restrict__ A,
                float* __restrict__ ws)
{
    __shared__ __align__(16) float skq_s[45 * SKST];    // 2160 B, e-major
    __shared__ __align__(16) float buf_s[SEGS * MATS];  // 47616 B tree buffer

    const int tid   = threadIdx.x;
    const int chain = blockIdx.x >> 2;   // / NCHK
    const int qt    = blockIdx.x & 3;
    const int n     = chain >> 1;        // / CC
    const int c     = chain & 1;

    // skq[e][ip] = sk-tri entry e of input dim ip (channel c). 360 entries.
    if (tid < 45 * 8) {
        const int e  = tid >> 3;
        const int ip = tid & 7;
        int k = 0, r2 = e;
        while (r2 >= 9 - k) { r2 -= (9 - k); ++k; }
        const int j = k + 1 + r2;
        const float* Ab = A + (size_t)(c * INQ + ip) * (MM * MM);
        skq_s[e * SKST + ip] = Ab[k * MM + j] - Ab[j * MM + k];
    }
    __syncthreads();

    const int wv  = tid >> 6;            // wave 0..7
    const int wl  = tid & 63;            // lane in wave
    const int g   = wl / 5;              // group 0..11 (12 = inactive tail)
    const int r   = wl - 5 * g;          // role 0..4 -> owns rows {2r, 2r+1}
    const bool act = (wl < 60);
    const int seg = wv * 12 + g;         // 0..95 active
    const int p0  = 2 * r;

    // Scratch slot (120 floats = 2 parities x 60), overlaid on buf_s.
    // Inactive lanes (g==12) write to dump slot 96; their reads alias the
    // next wave's slot 0 or the dump -- garbage in, discarded out.
    float* slot  = &buf_s[seg * SLOT];
    float* slotw = act ? slot : &buf_s[96 * SLOT];

    v2f R01[MM];
    #pragma unroll
    for (int j = 0; j < MM; ++j)
        R01[j] = (v2f){ (j == p0) ? 1.0f : 0.0f, (j == p0 + 1) ? 1.0f : 0.0f };

    const float4* px = reinterpret_cast<const float4*>(x + (size_t)n * TT * INQ);
    const int t0 = qt * (SEGS * SLEN) + seg * SLEN;   // padded timeline, < 2304
    const float* srow = &skq_s[(9 * r) * SKST];

    // Software pipeline over the scratch double-buffer.
    float tvv[9];
    compute_tvv(px, t0, srow, tvv);
    store_tvv(slotw, r, tvv);            // parity 0

    #pragma unroll 1
    for (int s = 0; s < SLEN - 1; ++s) {
        const int rpar = (s & 1) * 60;
        float Tri[45];
        load_tri(slot + rpar, Tri);            // data written 1 burst ago
        compute_tvv(px, t0 + s + 1, srow, tvv); // hides the read latency
        store_tvv(slotw + (60 - rpar), r, tvv); // opposite parity
        taylor5(Tri, R01);
    }
    {
        float Tri[45];
        load_tri(slot + ((SLEN - 1) & 1) * 60, Tri);
        taylor5(Tri, R01);
    }

    // Scratch phase over; buf_s becomes the tree buffer.
    __syncthreads();

    // Store segment product: each active lane stores its pair of rows.
    if (act) {
        float* dst = &buf_s[seg * MATS];
        float4* d0 = reinterpret_cast<float4*>(dst + p0 * ROWP);
        d0[0] = make_float4(R01[0].x, R01[1].x, R01[2].x, R01[3].x);
        d0[1] = make_float4(R01[4].x, R01[5].x, R01[6].x, R01[7].x);
        d0[2] = make_float4(R01[8].x, R01[9].x, 0.0f, 0.0f);
        float4* d1 = reinterpret_cast<float4*>(dst + (p0 + 1) * ROWP);
        d1[0] = make_float4(R01[0].y, R01[1].y, R01[2].y, R01[3].y);
        d1[1] = make_float4(R01[4].y, R01[5].y, R01[6].y, R01[7].y);
        d1[2] = make_float4(R01[8].y, R01[9].y, 0.0f, 0.0f);
    }
    __syncthreads();

    // Dyadic tree on 96 leaves: spans 2..32 -> products at {0,32,64},
    // then (0*32) and (0*64) sequential tail (time order preserved).
    #pragma unroll 1
    for (int span = 2; span <= 32; span <<= 1) {
        const int np = SEGS / span;
        if (tid < 2 * np) {
            const int pr = tid >> 1;
            const int pq = tid & 1;
            pair_combine(buf_s, pr * span, pr * span + (span >> 1), pq);
        }
        __syncthreads();
    }
    if (tid < 2) pair_combine(buf_s, 0, 32, tid);
    __syncthreads();
    if (tid < 2) pair_combine(buf_s, 0, 64, tid);
    __syncthreads();

    // Chunk product -> ws, padded 120 floats at (chain*NCHK + qt)
    if (tid < 30) {
        const float4 v = reinterpret_cast<const float4*>(buf_s)[tid];
        reinterpret_cast<float4*>(ws)[((size_t)chain * NCHK + qt) * 30 + tid] = v;
    }
}

// K2: one block per chain; combine its 4 chunk products (time order)
__global__ __launch_bounds__(256)
void dev_tree4(const float* __restrict__ ws, float* __restrict__ out)
{
    __shared__ __align__(16) float buf_s[4 * MATS];
    const int tid   = threadIdx.x;
    const int chain = blockIdx.x;

    if (tid < 120) {
        const int m  = tid / 30;
        const int o4 = tid - m * 30;
        const float4 v = reinterpret_cast<const float4*>(ws)[((size_t)chain * 4 + m) * 30 + o4];
        reinterpret_cast<float4*>(&buf_s[m * MATS])[o4] = v;
    }
    __syncthreads();

    if (tid < 4)
        pair_combine(buf_s, (tid >> 1) * 2, (tid >> 1) * 2 + 1, tid & 1);
    __syncthreads();
    if (tid < 2)
        pair_combine(buf_s, 0, 2, tid);
    __syncthreads();

    if (tid < 100) {
        const int i = tid / 10;
        const int j = tid - i * 10;
        out[(size_t)chain * 100 + tid] = buf_s[i * ROWP + j];
    }
}

extern "C" void kernel_launch(void* const* d_in, const int* in_sizes, int n_in,
                              void* d_out, int out_size, void* d_ws, size_t ws_size,
                              hipStream_t stream) {
    (void)in_sizes; (void)n_in; (void)out_size; (void)ws_size;
    const float* x = (const float*)d_in[0];  // (64, 2048, 8)
    const float* A = (const float*)d_in[1];  // (2, 8, 10, 10)
    float* out = (float*)d_out;              // (64, 2, 10, 10)
    float* ws  = (float*)d_ws;               // 512 mats * 480 B = 245,760 B

    dev_serial<<<dim3(NCHAIN * NCHK), dim3(BLK), 0, stream>>>(x, A, ws);
    dev_tree4<<<dim3(NCHAIN), dim3(256), 0, stream>>>(ws, out);
}

// Round 12
// 93.282 us; speedup vs baseline: 1.1418x; 1.1418x over previous
//
#include <hip/hip_runtime.h>

// Problem constants
#define NB     64      // batch
#define TT     2048    // time
#define INQ    8       // input size
#define CC     2       // channels
#define MM     10      // hidden m
#define ROWP   12      // padded row floats (48 B)
#define MATS   124     // matrix stride in LDS tree (124%32=28)
#define SKST   12      // skq row stride floats (48 B, b128-aligned)
#define BLK    512     // threads per block (8 waves)
#define SEGS   96      // 8 waves * 12 five-lane groups
#define SLEN   11      // steps per segment (padded timeline 2112 = 2*96*11, 3% pad)
#define NCHK   2       // chunks per chain -> grid 256 = 1 block/CU
#define NCHAIN (NB*CC)
#define SLOT   120     // scratch slot floats per group (2 parities x 60)

typedef float v2f __attribute__((ext_vector_type(2)));

static_assert(SEGS * MATS >= 97 * SLOT, "scratch overlay must fit tree buffer");

// Upper-triangle index for (k,j), k<j, into 45-element array
__device__ __forceinline__ constexpr int triIdx(int k, int j) {
    return k * 10 + j - ((k + 1) * (k + 2)) / 2;
}

// One Taylor row-stream, packed pair of rows: t = S*G; A = t; R += cj*t.
// Row r of S*G depends only on row r of S -> in-place safe (S may alias A).
__device__ __forceinline__ void trow_pk(const float* __restrict__ Tri,
                                        v2f* A, v2f* R, const v2f* S, float cj) {
    v2f t[MM];
    t[0] = -S[1] * Tri[triIdx(0, 1)];
    #pragma unroll
    for (int j = 1; j < MM; ++j) t[j] = S[0] * Tri[triIdx(0, j)];
    #pragma unroll
    for (int k = 1; k < MM; ++k) {
        const v2f a = S[k];
        #pragma unroll
        for (int j = 0; j < MM; ++j) {
            if (k == j) continue;
            if (j == 0 && k == 1) continue;
            if (j > k) t[j] += a * Tri[triIdx(k, j)];
            else       t[j] -= a * Tri[triIdx(j, k)];
        }
    }
    #pragma unroll
    for (int j = 0; j < MM; ++j) { A[j] = t[j]; R[j] += cj * t[j]; }
}

// KTAY=5 Taylor burst on the packed row-pair accumulator.
__device__ __forceinline__ void taylor5(const float* __restrict__ Tri, v2f* R01) {
    __builtin_amdgcn_s_setprio(1);
    v2f A01[MM];
    trow_pk(Tri, A01, R01, R01, 1.0f);
    trow_pk(Tri, A01, R01, A01, 0.5f);
    trow_pk(Tri, A01, R01, A01, 0.16666667f);
    trow_pk(Tri, A01, R01, A01, 0.041666668f);
    trow_pk(Tri, A01, R01, A01, 0.0083333338f);
    __builtin_amdgcn_s_setprio(0);
}

// tvv for one step: clamped x loads, dx, 9 dot-products against the
// REGISTER-resident skq rows (sg[2i], sg[2i+1] = row i halves).
__device__ __forceinline__ void compute_tvv(const float4* __restrict__ px, int t,
                                            const float4* __restrict__ sg,
                                            float* __restrict__ tvv) {
    const int tc = (t     > TT - 1) ? TT - 1 : t;
    const int t1 = (t + 1 > TT - 1) ? TT - 1 : t + 1;
    const float4 a0 = px[2 * tc], a1 = px[2 * tc + 1];
    const float4 b0 = px[2 * t1], b1 = px[2 * t1 + 1];
    float dx[INQ];
    dx[0] = b0.x - a0.x; dx[1] = b0.y - a0.y;
    dx[2] = b0.z - a0.z; dx[3] = b0.w - a0.w;
    dx[4] = b1.x - a1.x; dx[5] = b1.y - a1.y;
    dx[6] = b1.z - a1.z; dx[7] = b1.w - a1.w;
    #pragma unroll
    for (int i = 0; i < 9; ++i) {
        const float4 s0 = sg[2 * i];
        const float4 s1 = sg[2 * i + 1];
        tvv[i] = dx[0] * s0.x + dx[1] * s0.y + dx[2] * s0.z + dx[3] * s0.w
               + dx[4] * s1.x + dx[5] * s1.y + dx[6] * s1.z + dx[7] * s1.w;
    }
}

// Stage 9 tvv to the group scratch slot: 2 b128 + 1 b32 (48B-aligned lane slot).
__device__ __forceinline__ void store_tvv(float* __restrict__ dst, int r,
                                          const float* __restrict__ tvv) {
    *reinterpret_cast<float4*>(dst + 12 * r)     = make_float4(tvv[0], tvv[1], tvv[2], tvv[3]);
    *reinterpret_cast<float4*>(dst + 12 * r + 4) = make_float4(tvv[4], tvv[5], tvv[6], tvv[7]);
    dst[12 * r + 8] = tvv[8];
}

// Gather the group's 45 entries: 5 x (b128, b128, b32).
__device__ __forceinline__ void load_tri(const float* __restrict__ src,
                                         float* __restrict__ Tri) {
    #pragma unroll
    for (int q2 = 0; q2 < 5; ++q2) {
        const float4 u0 = *reinterpret_cast<const float4*>(src + 12 * q2);
        const float4 u1 = *reinterpret_cast<const float4*>(src + 12 * q2 + 4);
        const float  u2 = src[12 * q2 + 8];
        Tri[9 * q2 + 0] = u0.x; Tri[9 * q2 + 1] = u0.y;
        Tri[9 * q2 + 2] = u0.z; Tri[9 * q2 + 3] = u0.w;
        Tri[9 * q2 + 4] = u1.x; Tri[9 * q2 + 5] = u1.y;
        Tri[9 * q2 + 6] = u1.z; Tri[9 * q2 + 7] = u1.w;
        Tri[9 * q2 + 8] = u2;
    }
}

// 2-lane pair combine: buf[ls] <- buf[ls] * buf[rs] (pq = which 5-row half)
__device__ __forceinline__ void pair_combine(float* buf_s, int ls, int rs, int pq) {
    float lrow[5][MM];
    #pragma unroll
    for (int r = 0; r < 5; ++r) {
        const float4* lr = reinterpret_cast<const float4*>(
            &buf_s[ls * MATS + (pq * 5 + r) * ROWP]);
        const float4 a = lr[0], b = lr[1], c4 = lr[2];
        lrow[r][0] = a.x;  lrow[r][1] = a.y;  lrow[r][2] = a.z;  lrow[r][3] = a.w;
        lrow[r][4] = b.x;  lrow[r][5] = b.y;  lrow[r][6] = b.z;  lrow[r][7] = b.w;
        lrow[r][8] = c4.x; lrow[r][9] = c4.y;
    }
    float d[5][MM];
    #pragma unroll
    for (int r = 0; r < 5; ++r)
        #pragma unroll
        for (int j = 0; j < MM; ++j)
            d[r][j] = 0.0f;
    #pragma unroll
    for (int k = 0; k < MM; ++k) {
        const float4* rr = reinterpret_cast<const float4*>(&buf_s[rs * MATS + k * ROWP]);
        const float4 a = rr[0], b = rr[1], c4 = rr[2];
        float rrow[MM];
        rrow[0] = a.x;  rrow[1] = a.y;  rrow[2] = a.z;  rrow[3] = a.w;
        rrow[4] = b.x;  rrow[5] = b.y;  rrow[6] = b.z;  rrow[7] = b.w;
        rrow[8] = c4.x; rrow[9] = c4.y;
        #pragma unroll
        for (int r = 0; r < 5; ++r) {
            const float lv = lrow[r][k];
            #pragma unroll
            for (int j = 0; j < MM; ++j)
                d[r][j] += lv * rrow[j];
        }
    }
    float* dst = &buf_s[ls * MATS + pq * 5 * ROWP];
    #pragma unroll
    for (int r = 0; r < 5; ++r) {
        float4* drow = reinterpret_cast<float4*>(dst + r * ROWP);
        drow[0] = make_float4(d[r][0], d[r][1], d[r][2], d[r][3]);
        drow[1] = make_float4(d[r][4], d[r][5], d[r][6], d[r][7]);
        drow[2] = make_float4(d[r][8], d[r][9], 0.0f, 0.0f);
    }
}

// r23: occupancy lever closed (r17 pre-diet + r22 post-diet both null:
// more waves never reduced wall; per-CU throughput at 8 waves binds).
// Geometry reverts to r21 (best: serial 43.4, total 94.6). Single change:
// hoist the 9 skq rows (18 ds_read_b128/step = HALF the per-step LDS ops)
// into 18 float4 REGISTERS before the step loop -- they are loop-invariant
// per lane. VGPR rises 104 -> ~180, which is FREE: occupancy is pinned at
// 1 block/CU by LDS, and (512,1) allows up to 256 VGPR (r19's spill was
// at a 128 cap that no longer applies... verify via FETCH_SIZE ~4.3MB).
// LDS pipe/step/CU ~3400 -> ~1500 cyc; VALU (~3100) becomes the bound;
// parity pipeline (r21) keeps hiding the remaining Tri reads under the
// Taylor burst. Math bit-identical. KTAY=4 held in reserve.
__global__ __launch_bounds__(BLK, 1)
void dev_serial(const float* __restrict__ x,
                const float* __restrict__ A,
                float* __restrict__ ws)
{
    __shared__ __align__(16) float skq_s[45 * SKST];    // 2160 B, e-major
    __shared__ __align__(16) float buf_s[SEGS * MATS];  // 47616 B tree buffer

    const int tid   = threadIdx.x;
    const int chain = blockIdx.x >> 1;   // / NCHK
    const int qt    = blockIdx.x & 1;
    const int n     = chain >> 1;        // / CC
    const int c     = chain & 1;

    // skq[e][ip] = sk-tri entry e of input dim ip (channel c). 360 entries.
    if (tid < 45 * 8) {
        const int e  = tid >> 3;
        const int ip = tid & 7;
        int k = 0, r2 = e;
        while (r2 >= 9 - k) { r2 -= (9 - k); ++k; }
        const int j = k + 1 + r2;
        const float* Ab = A + (size_t)(c * INQ + ip) * (MM * MM);
        skq_s[e * SKST + ip] = Ab[k * MM + j] - Ab[j * MM + k];
    }
    __syncthreads();

    const int wv  = tid >> 6;            // wave 0..7
    const int wl  = tid & 63;            // lane in wave
    const int g   = wl / 5;              // group 0..11 (12 = inactive tail)
    const int r   = wl - 5 * g;          // role 0..4 -> owns rows {2r, 2r+1}
    const bool act = (wl < 60);
    const int seg = wv * 12 + g;         // 0..95 active
    const int p0  = 2 * r;

    // Hoist this lane's 9 skq rows into registers (loop-invariant).
    float4 sg[18];
    {
        const float* srow = &skq_s[(9 * r) * SKST];
        #pragma unroll
        for (int i = 0; i < 9; ++i) {
            sg[2 * i]     = *reinterpret_cast<const float4*>(srow + i * SKST);
            sg[2 * i + 1] = *reinterpret_cast<const float4*>(srow + i * SKST + 4);
        }
    }

    // Scratch slot (120 floats = 2 parities x 60), overlaid on buf_s.
    // Inactive lanes (g==12) write to dump slot 96; their reads alias the
    // next wave's slot 0 or the dump -- garbage in, discarded out.
    float* slot  = &buf_s[seg * SLOT];
    float* slotw = act ? slot : &buf_s[96 * SLOT];

    v2f R01[MM];
    #pragma unroll
    for (int j = 0; j < MM; ++j)
        R01[j] = (v2f){ (j == p0) ? 1.0f : 0.0f, (j == p0 + 1) ? 1.0f : 0.0f };

    const float4* px = reinterpret_cast<const float4*>(x + (size_t)n * TT * INQ);
    const int t0 = qt * (SEGS * SLEN) + seg * SLEN;   // padded timeline, < 2112

    // Software pipeline over the scratch double-buffer.
    float tvv[9];
    compute_tvv(px, t0, sg, tvv);
    store_tvv(slotw, r, tvv);            // parity 0

    #pragma unroll 1
    for (int s = 0; s < SLEN - 1; ++s) {
        const int rpar = (s & 1) * 60;
        float Tri[45];
        load_tri(slot + rpar, Tri);            // data written 1 burst ago
        compute_tvv(px, t0 + s + 1, sg, tvv);   // hides the read latency
        store_tvv(slotw + (60 - rpar), r, tvv); // opposite parity
        taylor5(Tri, R01);
    }
    {
        float Tri[45];
        load_tri(slot + ((SLEN - 1) & 1) * 60, Tri);
        taylor5(Tri, R01);
    }

    // Scratch phase over; buf_s becomes the tree buffer.
    __syncthreads();

    // Store segment product: each active lane stores its pair of rows.
    if (act) {
        float* dst = &buf_s[seg * MATS];
        float4* d0 = reinterpret_cast<float4*>(dst + p0 * ROWP);
        d0[0] = make_float4(R01[0].x, R01[1].x, R01[2].x, R01[3].x);
        d0[1] = make_float4(R01[4].x, R01[5].x, R01[6].x, R01[7].x);
        d0[2] = make_float4(R01[8].x, R01[9].x, 0.0f, 0.0f);
        float4* d1 = reinterpret_cast<float4*>(dst + (p0 + 1) * ROWP);
        d1[0] = make_float4(R01[0].y, R01[1].y, R01[2].y, R01[3].y);
        d1[1] = make_float4(R01[4].y, R01[5].y, R01[6].y, R01[7].y);
        d1[2] = make_float4(R01[8].y, R01[9].y, 0.0f, 0.0f);
    }
    __syncthreads();

    // Dyadic tree on 96 leaves: spans 2..32 -> products at {0,32,64},
    // then (0*32) and (0*64) sequential tail (time order preserved).
    #pragma unroll 1
    for (int span = 2; span <= 32; span <<= 1) {
        const int np = SEGS / span;
        if (tid < 2 * np) {
            const int pr = tid >> 1;
            const int pq = tid & 1;
            pair_combine(buf_s, pr * span, pr * span + (span >> 1), pq);
        }
        __syncthreads();
    }
    if (tid < 2) pair_combine(buf_s, 0, 32, tid);
    __syncthreads();
    if (tid < 2) pair_combine(buf_s, 0, 64, tid);
    __syncthreads();

    // Chunk product -> ws, padded 120 floats at (chain*NCHK + qt)
    if (tid < 30) {
        const float4 v = reinterpret_cast<const float4*>(buf_s)[tid];
        reinterpret_cast<float4*>(ws)[((size_t)chain * NCHK + qt) * 30 + tid] = v;
    }
}

// K2: one block per chain; combine its 2 chunk products (time order)
__global__ __launch_bounds__(256)
void dev_tree2(const float* __restrict__ ws, float* __restrict__ out)
{
    __shared__ __align__(16) float buf_s[2 * MATS];
    const int tid   = threadIdx.x;
    const int chain = blockIdx.x;

    if (tid < 60) {
        const int m  = tid / 30;
        const int o4 = tid - m * 30;
        const float4 v = reinterpret_cast<const float4*>(ws)[((size_t)chain * 2 + m) * 30 + o4];
        reinterpret_cast<float4*>(&buf_s[m * MATS])[o4] = v;
    }
    __syncthreads();

    if (tid < 2)
        pair_combine(buf_s, 0, 1, tid);
    __syncthreads();

    if (tid < 100) {
        const int i = tid / 10;
        const int j = tid - i * 10;
        out[(size_t)chain * 100 + tid] = buf_s[i * ROWP + j];
    }
}

extern "C" void kernel_launch(void* const* d_in, const int* in_sizes, int n_in,
                              void* d_out, int out_size, void* d_ws, size_t ws_size,
                              hipStream_t stream) {
    (void)in_sizes; (void)n_in; (void)out_size; (void)ws_size;
    const float* x = (const float*)d_in[0];  // (64, 2048, 8)
    const float* A = (const float*)d_in[1];  // (2, 8, 10, 10)
    float* out = (float*)d_out;              // (64, 2, 10, 10)
    float* ws  = (float*)d_ws;               // 256 mats * 480 B = 122,880 B

    dev_serial<<<dim3(NCHAIN * NCHK), dim3(BLK), 0, stream>>>(x, A, ws);
    dev_tree2<<<dim3(NCHAIN), dim3(256), 0, stream>>>(ws, out);
}